// Round 1
// 402.855 us; speedup vs baseline: 1.0673x; 1.0673x over previous
//
#include <hip/hip_runtime.h>
#include <hip/hip_bf16.h>

#define B_ 128
#define L_ 4096
#define D_ 128
#define E_ 64
#define GQ 8   // gather blocks per batch

typedef __attribute__((ext_vector_type(8))) short short8;
typedef __attribute__((ext_vector_type(4))) float floatx4;

// truncation split: hi = top-16-bit truncation (valid bf16), lo = x - hi (exact),
// lo also truncated to bf16. Combined rel error ~2^-16.
static __device__ __forceinline__ void split_trunc(float x, unsigned short& hs,
                                                   unsigned short& ls) {
  unsigned int bx = __float_as_uint(x);
  float hf = __uint_as_float(bx & 0xffff0000u);
  hs = (unsigned short)(bx >> 16);
  float lo = x - hf;
  ls = (unsigned short)(__float_as_uint(lo) >> 16);
}

// ---------------- prep: blocks 0..63 split+swizzle Wr1; blocks 64..127 compute
// cvec[b][d] = bias_r[d] + sum_e (target[b]·Wf_w[e] + Wf_b[e]) * Wr2[d][e]
__global__ __launch_bounds__(256) void prep(
    const float* __restrict__ Wr1, unsigned short* __restrict__ hi,
    unsigned short* __restrict__ lo, const float* __restrict__ target,
    const float* __restrict__ Wr2, const float* __restrict__ bias_r,
    const float* __restrict__ Wf_w, const float* __restrict__ Wf_b,
    float* __restrict__ cvec) {
  if (blockIdx.x < 64) {
    // B operand fragments: B[k=d][n=e] = Wr1[e][d]; dst [nt(8)][ks(4)][lane(64)][j(8)]
    int t = blockIdx.x * 256 + threadIdx.x;  // 0..16383
    int j = t & 7, lane = (t >> 3) & 63, ks = (t >> 9) & 3, nt = t >> 11;
    int e = nt * 16 + (lane & 15);
    int d = ks * 32 + (lane >> 4) * 8 + j;
    split_trunc(Wr1[e * D_ + d], hi[t], lo[t]);
  } else {
    const int sub = threadIdx.x >> 7;           // 2 batches per block
    const int t = threadIdx.x & 127;
    const int b = (blockIdx.x - 64) * 2 + sub;
    __shared__ float tg[2][D_];
    __shared__ float q[2][E_];
    tg[sub][t] = target[b * D_ + t];
    __syncthreads();
    if (t < E_) {
      float s = Wf_b[t];
      #pragma unroll 8
      for (int d = 0; d < D_; ++d) s += tg[sub][d] * Wf_w[t * D_ + d];
      q[sub][t] = s;
    }
    __syncthreads();
    float s = bias_r[t];
    #pragma unroll 8
    for (int e = 0; e < E_; ++e) s += q[sub][e] * Wr2[t * E_ + e];
    cvec[b * D_ + t] = s;
  }
}

// ---------------- pass B: scores[b][l] = sum_e Wr3[e]*relu( R[b][l]·Wr1[e] + c[b][e] )
// BM=64 tile, 8192 blocks, 4 blocks/CU (LDS 33 KB). Wave w stages m-tile w.
// CHANGE vs prev: epilogue shfl-reduce fused into the mt loop so only 2 acc
// fragments (8 VGPRs) are live instead of 8 (32) — keeps peak regs under the
// __launch_bounds__(256,4) 128-VGPR cap (spill elimination).
__global__ __launch_bounds__(256, 4) void pass_b(
    const float* __restrict__ R, const unsigned short* __restrict__ Whi,
    const unsigned short* __restrict__ Wlo, const float* __restrict__ cvec,
    const float* __restrict__ Wr3, float* __restrict__ scores) {
  __shared__ __align__(16) unsigned short sAhi[8192];  // 16 KB (64x128 hi)
  __shared__ __align__(16) unsigned short sAlo[8192];  // 16 KB (64x128 lo)
  __shared__ float red[256];                           // cross-wave reduce

  const int b = blockIdx.x >> 6;
  const int lt = blockIdx.x & 63;
  const int t = threadIdx.x;
  const int wave = t >> 6, lane = t & 63;
  const int col = lane & 15, quad = lane >> 4;

  // early L2-hot scalars (latency overlaps staging)
  float w3[2], cb[2];
  #pragma unroll
  for (int n = 0; n < 2; ++n) {
    const int e = (wave * 2 + n) * 16 + col;
    w3[n] = Wr3[e];
    cb[n] = cvec[b * D_ + e];
  }

  // ---- stage A tile: wave w owns m-tile w (rows lt*64 + w*16 + col)
  const float* Rbase = R + ((size_t)b * L_ + (size_t)lt * 64) * D_;
  #pragma unroll
  for (int ks = 0; ks < 4; ++ks) {
    const int row = wave * 16 + col;
    const int c0 = ks * 32 + quad * 8;
    const float4* p = (const float4*)(Rbase + (size_t)row * D_ + c0);
    float4 v0 = p[0], v1 = p[1];
    float vv[8] = {v0.x, v0.y, v0.z, v0.w, v1.x, v1.y, v1.z, v1.w};
    union { unsigned short u[8]; short8 v; } H, Lo;
    #pragma unroll
    for (int j = 0; j < 8; ++j) split_trunc(vv[j], H.u[j], Lo.u[j]);
    const int base = ((wave * 4 + ks) * 64 + lane) * 8;
    *(short8*)(sAhi + base) = H.v;
    *(short8*)(sAlo + base) = Lo.v;
  }

  // ---- preload this wave's pre-split B fragments (2 nt x 4 ks, hi+lo)
  short8 bh[2][4], bl[2][4];
  #pragma unroll
  for (int n = 0; n < 2; ++n)
    #pragma unroll
    for (int ks = 0; ks < 4; ++ks) {
      const int off = (((wave * 2 + n) * 4 + ks) * 64 + lane) * 8;
      bh[n][ks] = *(const short8*)(Whi + off);
      bl[n][ks] = *(const short8*)(Wlo + off);
    }

  __syncthreads();

  // ---- MFMA loop (split-bf16: hi*hi + lo*hi + hi*lo), per-mt fused epilogue
  float part[4][4];
  #pragma unroll
  for (int mt = 0; mt < 4; ++mt) {
    floatx4 acc[2];
    acc[0] = (floatx4){0.f, 0.f, 0.f, 0.f};
    acc[1] = (floatx4){0.f, 0.f, 0.f, 0.f};
    #pragma unroll
    for (int ks = 0; ks < 4; ++ks) {
      const int ai = ((mt * 4 + ks) * 64 + lane) * 8;
      short8 ah = *(const short8*)(sAhi + ai);
      short8 al = *(const short8*)(sAlo + ai);
      #pragma unroll
      for (int n = 0; n < 2; ++n) {
        acc[n] = __builtin_amdgcn_mfma_f32_16x16x32_bf16(ah, bh[n][ks], acc[n], 0, 0, 0);
        acc[n] = __builtin_amdgcn_mfma_f32_16x16x32_bf16(al, bh[n][ks], acc[n], 0, 0, 0);
        acc[n] = __builtin_amdgcn_mfma_f32_16x16x32_bf16(ah, bl[n][ks], acc[n], 0, 0, 0);
      }
    }
    // score[m] = sum_e Wr3[e]*relu(C[m][e] + cvec[e]) — partial over this wave's e
    #pragma unroll
    for (int r = 0; r < 4; ++r) {
      float s = 0.f;
      #pragma unroll
      for (int n = 0; n < 2; ++n)
        s += w3[n] * fmaxf(acc[n][r] + cb[n], 0.f);
      s += __shfl_xor(s, 1, 64);
      s += __shfl_xor(s, 2, 64);
      s += __shfl_xor(s, 4, 64);
      s += __shfl_xor(s, 8, 64);
      part[mt][r] = s;
    }
  }

  if (col == 0) {
    #pragma unroll
    for (int mt = 0; mt < 4; ++mt)
      #pragma unroll
      for (int r = 0; r < 4; ++r)
        red[wave * 64 + mt * 16 + quad * 4 + r] = part[mt][r];
  }
  __syncthreads();
  if (t < 64) {
    float s = (red[t] + red[64 + t]) + (red[128 + t] + red[192 + t]);
    scores[(size_t)b * L_ + lt * 64 + t] = s;
  }
}

// ---------------- pass C: entmax bisection (24 iters, numerics identical to
// previous version) + support compaction. Writes compacted (idx, p/sum) list
// + count to workspace; gather moved to its own wide kernel.
__global__ __launch_bounds__(512) void pass_c(
    const float* __restrict__ scores, const float* __restrict__ alpha,
    unsigned short* __restrict__ sidxg, float* __restrict__ swg,
    int* __restrict__ cntg) {
  const int b = blockIdx.x, t = threadIdx.x;
  const int wave = t >> 6, lane = t & 63;
  __shared__ float sred[2][8];
  __shared__ unsigned short sidx[L_];
  __shared__ float sw[L_];
  __shared__ int scnt;
  const float am1 = alpha[b] - 1.0f;
  const float inv = 1.0f / am1;
  const float* S = scores + (size_t)b * L_;
  float Xs[8];
  #pragma unroll
  for (int i = 0; i < 8; ++i) Xs[i] = S[i * 512 + t] * am1;
  if (t == 0) scnt = 0;

  // block max
  float mx = Xs[0];
  #pragma unroll
  for (int i = 1; i < 8; ++i) mx = fmaxf(mx, Xs[i]);
  #pragma unroll
  for (int m = 32; m >= 1; m >>= 1) mx = fmaxf(mx, __shfl_xor(mx, m, 64));
  if (lane == 0) sred[0][wave] = mx;
  __syncthreads();
  mx = sred[0][0];
  #pragma unroll
  for (int w = 1; w < 8; ++w) mx = fmaxf(mx, sred[0][w]);

  float tau_lo = mx - 1.0f;
  float dm = (mx - exp2f(-12.0f * am1)) - tau_lo;  // tau_hi - tau_lo

  int pc = 1;  // parity counter (buffer 0 used by max)
  auto sumP = [&](float tau) -> float {
    const int par = pc & 1;
    ++pc;
    float s = 0.f;
    #pragma unroll
    for (int i = 0; i < 8; ++i) {
      float u = Xs[i] - tau;
      if (u > 0.f) s += exp2f(inv * __log2f(u));
    }
    #pragma unroll
    for (int m = 32; m >= 1; m >>= 1) s += __shfl_xor(s, m, 64);
    if (lane == 0) sred[par][wave] = s;
    __syncthreads();
    float r = sred[par][0];
    #pragma unroll
    for (int w = 1; w < 8; ++w) r += sred[par][w];
    return r;
  };

  const float f_lo = sumP(tau_lo) - 1.0f;
  float tau_m = tau_lo;
  for (int it = 0; it < 24; ++it) {  // dtau = bracket*2^-24: output shift << thresh
    dm *= 0.5f;
    tau_m = tau_lo + dm;
    float f_m = sumP(tau_m) - 1.0f;
    if (f_m * f_lo >= 0.f) tau_lo = tau_m;  // uniform branch
  }

  // final p, compact support, normalization sum
  float s = 0.f;
  #pragma unroll
  for (int i = 0; i < 8; ++i) {
    float u = Xs[i] - tau_m;
    if (u > 0.f) {
      float p = exp2f(inv * __log2f(u));
      s += p;
      int pos = atomicAdd(&scnt, 1);
      sidx[pos] = (unsigned short)(i * 512 + t);
      sw[pos] = p;
    }
  }
  {
    const int par = pc & 1;
    ++pc;
    #pragma unroll
    for (int m = 32; m >= 1; m >>= 1) s += __shfl_xor(s, m, 64);
    if (lane == 0) sred[par][wave] = s;
    __syncthreads();  // publishes sidx/sw/scnt too
    s = sred[par][0];
    #pragma unroll
    for (int w = 1; w < 8; ++w) s += sred[par][w];
  }
  const int ns = scnt;
  const float rs = 1.0f / s;

  // dump compacted, pre-normalized support list to workspace (coalesced)
  for (int j = t; j < ns; j += 512) {
    sidxg[(size_t)b * L_ + j] = sidx[j];
    swg[(size_t)b * L_ + j] = sw[j] * rs;
  }
  if (t == 0) cntg[b] = ns;
}

// ---------------- pass G: weighted gather res_partial = sum_k w_k * R[b, i_k, :]
// 8 blocks per batch (contiguous k-slices), 8 k-lanes x 32 d-threads per block,
// manual 4-deep unroll → ~16 KB/block of loads in flight (ILP for HBM latency).
__global__ __launch_bounds__(256) void pass_g(
    const unsigned short* __restrict__ sidxg, const float* __restrict__ swg,
    const int* __restrict__ cntg, const float* __restrict__ R,
    float* __restrict__ partial) {
  const int b = blockIdx.x >> 3, q = blockIdx.x & 7;
  const int t = threadIdx.x;
  const int ns = cntg[b];
  const int per = (ns + GQ - 1) / GQ;
  const int k0 = q * per;
  int len = ns - k0;
  if (len > per) len = per;
  if (len < 0) len = 0;  // ns < k0 for trailing blocks

  __shared__ unsigned short si[512];
  __shared__ float swl[512];
  __shared__ floatx4 red4[8][32];

  for (int j = t; j < len; j += 256) {
    si[j] = sidxg[(size_t)b * L_ + k0 + j];
    swl[j] = swg[(size_t)b * L_ + k0 + j];
  }
  __syncthreads();

  const int dq = t & 31, sl = t >> 5;  // 32 d-columns (float4), 8 k-slices
  const floatx4* R4 = (const floatx4*)(R + (size_t)b * L_ * D_);
  floatx4 acc = (floatx4){0.f, 0.f, 0.f, 0.f};
  int j = sl;
  for (; j + 24 < len; j += 32) {  // 4 independent rows in flight per thread
    const int i0 = si[j], i1 = si[j + 8], i2 = si[j + 16], i3 = si[j + 24];
    const float w0 = swl[j], w1 = swl[j + 8], w2 = swl[j + 16], w3 = swl[j + 24];
    floatx4 r0 = R4[i0 * 32 + dq];
    floatx4 r1 = R4[i1 * 32 + dq];
    floatx4 r2 = R4[i2 * 32 + dq];
    floatx4 r3 = R4[i3 * 32 + dq];
    acc += w0 * r0;
    acc += w1 * r1;
    acc += w2 * r2;
    acc += w3 * r3;
  }
  for (; j < len; j += 8) acc += swl[j] * R4[si[j] * 32 + dq];

  red4[sl][dq] = acc;
  __syncthreads();
  if (t < 32) {
    floatx4 s = red4[0][t];
    #pragma unroll
    for (int w = 1; w < 8; ++w) s += red4[w][t];
    *(floatx4*)(partial + (((size_t)b * GQ + q) * 32 + t) * 4) = s;
  }
}

// ---------------- pass F: combine 8 partials, selu, L2-normalize, write out
__global__ __launch_bounds__(128) void pass_f(const float* __restrict__ partial,
                                              float* __restrict__ out) {
  const int b = blockIdx.x, t = threadIdx.x;
  const int wave = t >> 6, lane = t & 63;
  __shared__ float s2[2];
  float v = 0.f;
  #pragma unroll
  for (int q = 0; q < GQ; ++q) v += partial[((size_t)b * GQ + q) * D_ + t];
  const float sc = 1.0507009873554805f, al = 1.6732632423543772f;
  float r = v > 0.f ? sc * v : sc * al * (expf(v) - 1.0f);
  float qq = r * r;
  #pragma unroll
  for (int m = 32; m >= 1; m >>= 1) qq += __shfl_xor(qq, m, 64);
  if (lane == 0) s2[wave] = qq;
  __syncthreads();
  const float nrm = sqrtf(s2[0] + s2[1]);
  out[(size_t)b * D_ + t] = r / nrm;
}

extern "C" void kernel_launch(void* const* d_in, const int* in_sizes, int n_in,
                              void* d_out, int out_size, void* d_ws, size_t ws_size,
                              hipStream_t stream) {
  const float* R      = (const float*)d_in[0];
  const float* alpha  = (const float*)d_in[1];
  const float* target = (const float*)d_in[2];
  const float* Wr1    = (const float*)d_in[3];
  const float* Wr2    = (const float*)d_in[4];
  const float* Wr3    = (const float*)d_in[5];
  const float* bias_r = (const float*)d_in[6];
  const float* Wf_w   = (const float*)d_in[7];
  const float* Wf_b   = (const float*)d_in[8];
  float* out = (float*)d_out;

  char* ws = (char*)d_ws;
  float* cvec          = (float*)ws;                         // 64 KB
  unsigned short* whi  = (unsigned short*)(ws + 65536);      // 32 KB
  unsigned short* wlo  = (unsigned short*)(ws + 98304);      // 32 KB
  float* scores        = (float*)(ws + 131072);              // 2 MB
  unsigned short* sidxg= (unsigned short*)(ws + 2228224);    // 1 MB
  float* swg           = (float*)(ws + 3276800);             // 2 MB
  int* cntg            = (int*)(ws + 5373952);               // 512 B
  float* partial       = (float*)(ws + 5374464);             // 512 KB

  hipLaunchKernelGGL(prep, dim3(128), dim3(256), 0, stream,
                     Wr1, whi, wlo, target, Wr2, bias_r, Wf_w, Wf_b, cvec);
  hipLaunchKernelGGL(pass_b, dim3(B_ * 64), dim3(256), 0, stream,
                     R, whi, wlo, cvec, Wr3, scores);
  hipLaunchKernelGGL(pass_c, dim3(B_), dim3(512), 0, stream,
                     scores, alpha, sidxg, swg, cntg);
  hipLaunchKernelGGL(pass_g, dim3(B_ * GQ), dim3(256), 0, stream,
                     sidxg, swg, cntg, R, partial);
  hipLaunchKernelGGL(pass_f, dim3(B_), dim3(128), 0, stream,
                     partial, out);
}